// Round 1
// 754.971 us; speedup vs baseline: 1.1776x; 1.1776x over previous
//
#include <hip/hip_runtime.h>
#include <hip/hip_bf16.h>

// QuantumAttention: B=4, S=1024, E=1024, H=16, HD=64.
// Inputs/outputs fp32 (per reference); internal MFMA compute in bf16.
// d_out = [ out (4,194,304 f32) | probs_mixed (67,108,864 f32) ].
//
// R1 changes vs 890us baseline:
//  - 4 dense E*E GEMMs (q/k/v/out) -> m97-recipe 128x128 tile, BK=32,
//    global_load_lds width=16 staging (874 TF structure) instead of
//    direct-global 64^2 tile.
//  - attn_kernel: scores fully register-resident (64 f32/lane), softmax via
//    shfl + 256B LDS combine; removes 64KB LDS buffer (2 blk/CU cap).

#define S_ 1024
#define E_ 1024
#define H_ 16
#define HD_ 64
#define B_ 4

typedef __bf16 bf16x8 __attribute__((ext_vector_type(8)));
typedef __bf16 bf16x4 __attribute__((ext_vector_type(4)));
typedef float f32x4 __attribute__((ext_vector_type(4)));

// ---------- load helpers: 8 contiguous elements -> bf16x8 MFMA fragment
__device__ inline bf16x8 ld8(const __bf16* p) { return *(const bf16x8*)p; }
__device__ inline bf16x8 ld8(const float* p) {
    f32x4 u0 = *(const f32x4*)p;
    f32x4 u1 = *(const f32x4*)(p + 4);
    bf16x8 r;
    r[0] = (__bf16)u0[0]; r[1] = (__bf16)u0[1]; r[2] = (__bf16)u0[2]; r[3] = (__bf16)u0[3];
    r[4] = (__bf16)u1[0]; r[5] = (__bf16)u1[1]; r[6] = (__bf16)u1[2]; r[7] = (__bf16)u1[3];
    return r;
}
__device__ inline void stc(__bf16* p, float v) { *p = (__bf16)v; }
__device__ inline void stc(float* p, float v) { *p = v; }

// ---------- async global->LDS, 16B per lane. HW writes wave-uniform base + lane*16;
// LDS layout must be linear in lane order (it is: 1KB chunks, see gemm_bt_tiled).
__device__ inline void gld16(const __bf16* g, __bf16* l) {
    __builtin_amdgcn_global_load_lds(
        (const __attribute__((address_space(1))) unsigned int*)g,
        (__attribute__((address_space(3))) unsigned int*)l,
        16, 0, 0);
}

// ---------- fp32 -> bf16 cast, 8 elems/thread, up to 3 tensors per launch
__global__ __launch_bounds__(256) void cast3_kernel(
    const float* __restrict__ a, const float* __restrict__ b2, const float* __restrict__ c,
    __bf16* __restrict__ oa, __bf16* __restrict__ ob, __bf16* __restrict__ oc)
{
    int which = blockIdx.y;
    const float* in = which == 0 ? a : (which == 1 ? b2 : c);
    __bf16* out = which == 0 ? oa : (which == 1 ? ob : oc);
    long i = ((long)blockIdx.x * 256 + threadIdx.x) * 8;
    f32x4 u0 = *(const f32x4*)(in + i);
    f32x4 u1 = *(const f32x4*)(in + i + 4);
    bf16x8 r;
    r[0] = (__bf16)u0[0]; r[1] = (__bf16)u0[1]; r[2] = (__bf16)u0[2]; r[3] = (__bf16)u0[3];
    r[4] = (__bf16)u1[0]; r[5] = (__bf16)u1[1]; r[6] = (__bf16)u1[2]; r[7] = (__bf16)u1[3];
    *(bf16x8*)(out + i) = r;
}

// ---------- Weff[h*64+e, j] = cos(phase[h,e]) * sum_d Had[d,e] * W[h*64+d, j]
__global__ __launch_bounds__(256) void eff_weight_kernel(
    const float* __restrict__ W, const float* __restrict__ had,
    const float* __restrict__ phase, __bf16* __restrict__ Weff)
{
    int g = blockIdx.x * 256 + threadIdx.x;   // over E*E
    int row = g >> 10;                         // h*64+e
    int j = g & 1023;
    int h = row >> 6, e = row & 63;
    float c = cosf(phase[row]);
    float acc = 0.f;
#pragma unroll 8
    for (int d = 0; d < 64; ++d)
        acc += had[d * 64 + e] * W[(((h << 6) + d) << 10) + j];
    Weff[g] = (__bf16)(acc * c);
}

__global__ __launch_bounds__(256) void eff_bias_kernel(
    const float* __restrict__ bvec, const float* __restrict__ had,
    const float* __restrict__ phase, float* __restrict__ beff)
{
    int row = blockIdx.x * 256 + threadIdx.x;  // over E
    int e = row & 63, h = row >> 6;
    float acc = 0.f;
#pragma unroll 8
    for (int d = 0; d < 64; ++d)
        acc += had[d * 64 + e] * bvec[(h << 6) + d];
    beff[row] = acc * cosf(phase[row]);
}

// ---------- legacy BT GEMM (kept for PV step only: A=f32 probs, batched)
template <typename AT, typename CT>
__global__ __launch_bounds__(256) void gemm_bt(
    const AT* __restrict__ A, long lda, long sA1, long sA2,
    const __bf16* __restrict__ B, long ldb, long sB1, long sB2,
    CT* __restrict__ C, long ldc, long sC1, long sC2,
    const float* __restrict__ bias, int K, float alpha)
{
    int z = blockIdx.z, z1 = z >> 4, z2 = z & 15;
    const AT* Ab = A + (long)z1 * sA1 + (long)z2 * sA2;
    const __bf16* Bb = B + (long)z1 * sB1 + (long)z2 * sB2;
    CT* Cb = C + (long)z1 * sC1 + (long)z2 * sC2;

    int w = threadIdx.x >> 6, l = threadIdx.x & 63;
    int q = l >> 4, lm = l & 15;
    int ko = q * 8;
    long r0 = (long)blockIdx.x * 64 + (w >> 1) * 32 + lm;
    long c0 = (long)blockIdx.y * 64 + (w & 1) * 32 + lm;

    f32x4 acc00 = {0.f, 0.f, 0.f, 0.f};
    f32x4 acc01 = acc00, acc10 = acc00, acc11 = acc00;
    const AT* pa0 = Ab + r0 * lda + ko;
    const AT* pa1 = pa0 + 16 * lda;
    const __bf16* pb0 = Bb + c0 * ldb + ko;
    const __bf16* pb1 = pb0 + 16 * ldb;

    for (int k = 0; k < K; k += 32) {
        bf16x8 a0 = ld8(pa0 + k);
        bf16x8 a1 = ld8(pa1 + k);
        bf16x8 b0 = ld8(pb0 + k);
        bf16x8 b1 = ld8(pb1 + k);
        acc00 = __builtin_amdgcn_mfma_f32_16x16x32_bf16(a0, b0, acc00, 0, 0, 0);
        acc01 = __builtin_amdgcn_mfma_f32_16x16x32_bf16(a0, b1, acc01, 0, 0, 0);
        acc10 = __builtin_amdgcn_mfma_f32_16x16x32_bf16(a1, b0, acc10, 0, 0, 0);
        acc11 = __builtin_amdgcn_mfma_f32_16x16x32_bf16(a1, b1, acc11, 0, 0, 0);
    }

    f32x4 accs[2][2] = {{acc00, acc01}, {acc10, acc11}};
    long rbase = (long)blockIdx.x * 64 + (w >> 1) * 32 + q * 4;
    long cbase = (long)blockIdx.y * 64 + (w & 1) * 32 + lm;
#pragma unroll
    for (int i = 0; i < 2; ++i)
#pragma unroll
        for (int j = 0; j < 2; ++j) {
            long col = cbase + j * 16;
            float bv = bias ? bias[col] : 0.f;
#pragma unroll
            for (int rr = 0; rr < 4; ++rr) {
                long row = rbase + i * 16 + rr;
                stc(&Cb[row * ldc + col], accs[i][j][rr] * alpha + bv);
            }
        }
}

// ---------- m97-style tiled GEMM: C = (A @ B^T) + bias
// A:[M,K] bf16, B:[N,K] bf16, C:[M,N]. 128x128 tile, BK=32, 4 waves (2x2),
// 4x4 16x16x32 fragments/wave, global_load_lds(16B) staging, 2-barrier loop.
// grid (M/128, N/128), block 256.
template <typename CT>
__global__ __launch_bounds__(256) void gemm_bt_tiled(
    const __bf16* __restrict__ A, const __bf16* __restrict__ B,
    CT* __restrict__ C, const float* __restrict__ bias, int K, int ldc)
{
    __shared__ __bf16 As[128 * 32];   // 8 KB, row-major [128][32]
    __shared__ __bf16 Bs[128 * 32];   // 8 KB
    int t = threadIdx.x;
    int w = t >> 6, l = t & 63;
    int lm = l & 15, kq = l >> 4;
    int wm = w >> 1, wn = w & 1;
    long row0 = (long)blockIdx.x * 128;
    long col0 = (long)blockIdx.y * 128;

    // staging: LDS is 8 chunks of 1KB (16 rows x 32 cols bf16); wave w owns
    // chunks 2w, 2w+1 of each tile. lane l covers row (l>>2), cols (l&3)*8..+8.
    int srow = l >> 2, skol = (l & 3) * 8;
    int c0i = w * 2, c1i = w * 2 + 1;
    const __bf16* gA0 = A + (row0 + c0i * 16 + srow) * (long)K + skol;
    const __bf16* gA1 = A + (row0 + c1i * 16 + srow) * (long)K + skol;
    const __bf16* gB0 = B + (col0 + c0i * 16 + srow) * (long)K + skol;
    const __bf16* gB1 = B + (col0 + c1i * 16 + srow) * (long)K + skol;
    __bf16* lA0 = &As[c0i * 512];
    __bf16* lA1 = &As[c1i * 512];
    __bf16* lB0 = &Bs[c0i * 512];
    __bf16* lB1 = &Bs[c1i * 512];

    f32x4 acc[4][4] = {};
    for (int k0 = 0; k0 < K; k0 += 32) {
        gld16(gA0 + k0, lA0);
        gld16(gA1 + k0, lA1);
        gld16(gB0 + k0, lB0);
        gld16(gB1 + k0, lB1);
        __syncthreads();   // compiler emits s_waitcnt vmcnt(0) before barrier
        bf16x8 af[4], bfr[4];
#pragma unroll
        for (int i = 0; i < 4; ++i)
            af[i] = *(const bf16x8*)&As[(wm * 64 + i * 16 + lm) * 32 + kq * 8];
#pragma unroll
        for (int j = 0; j < 4; ++j)
            bfr[j] = *(const bf16x8*)&Bs[(wn * 64 + j * 16 + lm) * 32 + kq * 8];
#pragma unroll
        for (int i = 0; i < 4; ++i)
#pragma unroll
            for (int j = 0; j < 4; ++j)
                acc[i][j] = __builtin_amdgcn_mfma_f32_16x16x32_bf16(af[i], bfr[j], acc[i][j], 0, 0, 0);
        __syncthreads();
    }

    // epilogue: C/D layout col=lane&15, row=(lane>>4)*4+reg  [m89-verified]
    long rbase = row0 + wm * 64 + kq * 4;
    long cbase = col0 + wn * 64 + lm;
#pragma unroll
    for (int i = 0; i < 4; ++i)
#pragma unroll
        for (int j = 0; j < 4; ++j) {
            long col = cbase + j * 16;
            float bv = bias ? bias[col] : 0.f;
#pragma unroll
            for (int rr = 0; rr < 4; ++rr) {
                long row = rbase + i * 16 + rr;
                stc(&C[row * (long)ldc + col], acc[i][j][rr] + bv);
            }
        }
}

// ---------- V2 [B,S,E] bf16 -> Vt [B,H,64,S] bf16
__global__ __launch_bounds__(256) void transpose_v(
    const __bf16* __restrict__ v2, __bf16* __restrict__ vt)
{
    int blk = blockIdx.x;            // b*256 + h*16 + st
    int st = blk & 15;
    int h = (blk >> 4) & 15;
    int b = blk >> 8;
    __shared__ __bf16 tile[64][72];
    int t = threadIdx.x;
    int sl = t >> 2, dc = (t & 3) * 16;
    const __bf16* src = v2 + ((long)(b * 1024 + st * 64 + sl)) * 1024 + h * 64 + dc;
    bf16x8 u0 = *(const bf16x8*)src;
    bf16x8 u1 = *(const bf16x8*)(src + 8);
#pragma unroll
    for (int j = 0; j < 8; ++j) { tile[sl][dc + j] = u0[j]; tile[sl][dc + 8 + j] = u1[j]; }
    __syncthreads();
    int dl = t >> 2, scn = (t & 3) * 16;
    __bf16* dst = vt + ((long)((b * 16 + h) * 64 + dl)) * 1024 + st * 64 + scn;
    bf16x8 o0, o1;
#pragma unroll
    for (int j = 0; j < 8; ++j) { o0[j] = tile[scn + j][dl]; o1[j] = tile[scn + 8 + j][dl]; }
    *(bf16x8*)dst = o0;
    *(bf16x8*)(dst + 8) = o1;
}

// ---------- fused scores + softmax, register-resident scores.
// grid: (S/16, 1, B*H); block 256 (4 waves). Block = 16 q-rows x 1024 keys.
// Wave w covers key cols [w*256, w*256+256) = 16 MFMA f-tiles; each lane holds
// its 64 score f32 in regs (acc[16] f32x4). Softmax: in-lane reduce over f,
// shfl over the 16-lane row group, 256B-LDS combine across the 4 waves.
__global__ __launch_bounds__(256) void attn_kernel(
    const __bf16* __restrict__ Q2, const __bf16* __restrict__ K2,
    float* __restrict__ probs)
{
    __shared__ float redm[16][4] __attribute__((aligned(16)));
    __shared__ float reds[16][4] __attribute__((aligned(16)));
    int z = blockIdx.z;              // b*16 + h
    int b = z >> 4, h = z & 15;
    int qt = blockIdx.x;
    int w = threadIdx.x >> 6, l = threadIdx.x & 63;
    int q = l >> 4, lm = l & 15;
    int ko = q * 8;

    const __bf16* Qb = Q2 + (long)b * S_ * E_ + (long)h * 64;
    const __bf16* Kb = K2 + (long)b * S_ * E_ + (long)h * 64;

    const __bf16* pa = Qb + (long)(qt * 16 + lm) * E_ + ko;
    bf16x8 a0 = *(const bf16x8*)pa;
    bf16x8 a1 = *(const bf16x8*)(pa + 32);

    f32x4 acc[16];
#pragma unroll
    for (int f = 0; f < 16; ++f) {
        int n0 = w * 256 + f * 16;
        const __bf16* pb = Kb + (long)(n0 + lm) * E_ + ko;
        bf16x8 b0 = *(const bf16x8*)pb;
        bf16x8 b1 = *(const bf16x8*)(pb + 32);
        f32x4 tt = {0.f, 0.f, 0.f, 0.f};
        tt = __builtin_amdgcn_mfma_f32_16x16x32_bf16(a0, b0, tt, 0, 0, 0);
        tt = __builtin_amdgcn_mfma_f32_16x16x32_bf16(a1, b1, tt, 0, 0, 0);
        acc[f] = tt;
    }

    // lane holds rows q*4+rr (rr=0..3), cols w*256 + f*16 + lm.
    float m[4];
#pragma unroll
    for (int rr = 0; rr < 4; ++rr) {
        float mm = acc[0][rr];
#pragma unroll
        for (int f = 1; f < 16; ++f) mm = fmaxf(mm, acc[f][rr]);
#pragma unroll
        for (int off = 1; off < 16; off <<= 1) mm = fmaxf(mm, __shfl_xor(mm, off, 64));
        m[rr] = mm;
    }
    if (lm == 0) {
#pragma unroll
        for (int rr = 0; rr < 4; ++rr) redm[q * 4 + rr][w] = m[rr];
    }
    __syncthreads();
#pragma unroll
    for (int rr = 0; rr < 4; ++rr) {
        f32x4 v = *(const f32x4*)redm[q * 4 + rr];
        m[rr] = fmaxf(fmaxf(v[0], v[1]), fmaxf(v[2], v[3]));
    }

    float s[4] = {0.f, 0.f, 0.f, 0.f};
#pragma unroll
    for (int f = 0; f < 16; ++f) {
        f32x4 tt = acc[f];
#pragma unroll
        for (int rr = 0; rr < 4; ++rr) {
            float p = __expf((tt[rr] - m[rr]) * 0.125f);
            tt[rr] = p;
            s[rr] += p;
        }
        acc[f] = tt;
    }
#pragma unroll
    for (int rr = 0; rr < 4; ++rr) {
#pragma unroll
        for (int off = 1; off < 16; off <<= 1) s[rr] += __shfl_xor(s[rr], off, 64);
    }
    if (lm == 0) {
#pragma unroll
        for (int rr = 0; rr < 4; ++rr) reds[q * 4 + rr][w] = s[rr];
    }
    __syncthreads();
    float inv[4];
#pragma unroll
    for (int rr = 0; rr < 4; ++rr) {
        f32x4 v = *(const f32x4*)reds[q * 4 + rr];
        inv[rr] = 1.0f / (v[0] + v[1] + v[2] + v[3]);
    }

    float* prow = probs + (long)z * S_ * S_ + (long)(qt * 16) * S_;
#pragma unroll
    for (int f = 0; f < 16; ++f) {
        int col = w * 256 + f * 16 + lm;
#pragma unroll
        for (int rr = 0; rr < 4; ++rr)
            prow[(long)(q * 4 + rr) * S_ + col] = acc[f][rr] * inv[rr];
    }
}

// ---------- in-place head mix (f32): probs[b,g,q,k] = sum_h probs[b,h,q,k]*mask[h,g]
__global__ __launch_bounds__(256) void mix_kernel(
    float* __restrict__ probs, const float* __restrict__ mask)
{
    __shared__ float mm[256];
    int t = threadIdx.x;
    mm[t] = mask[t];
    __syncthreads();
    long gid = (long)blockIdx.x * 256 + t;      // over B*S*S/4
    long e4 = gid * 4;
    int b = (int)(e4 >> 20);                    // S*S = 2^20
    long rem = e4 & 1048575;
    float* base = probs + ((long)b << 24) + rem;   // b*H*S*S + rem
    f32x4 acc[16];
#pragma unroll
    for (int g = 0; g < 16; ++g) acc[g] = (f32x4){0.f, 0.f, 0.f, 0.f};
#pragma unroll
    for (int hh = 0; hh < 16; ++hh) {
        f32x4 vv = *(const f32x4*)(base + ((long)hh << 20));
#pragma unroll
        for (int g = 0; g < 16; ++g) acc[g] += vv * mm[hh * 16 + g];
    }
#pragma unroll
    for (int g = 0; g < 16; ++g) *(f32x4*)(base + ((long)g << 20)) = acc[g];
}

extern "C" void kernel_launch(void* const* d_in, const int* in_sizes, int n_in,
                              void* d_out, int out_size, void* d_ws, size_t ws_size,
                              hipStream_t stream) {
    (void)in_sizes; (void)n_in; (void)out_size; (void)ws_size;
    const float* query = (const float*)d_in[0];
    const float* key   = (const float*)d_in[1];
    const float* value = (const float*)d_in[2];
    const float* Wq    = (const float*)d_in[3];
    const float* bq    = (const float*)d_in[4];
    const float* Wk    = (const float*)d_in[5];
    const float* bk    = (const float*)d_in[6];
    const float* Wv    = (const float*)d_in[7];
    const float* bv    = (const float*)d_in[8];
    const float* Wo    = (const float*)d_in[9];
    const float* bo    = (const float*)d_in[10];
    const float* phase = (const float*)d_in[11];
    const float* had   = (const float*)d_in[12];
    const float* mask  = (const float*)d_in[13];

    // workspace layout (bf16 elems unless noted); ~56 MB total
    __bf16* wqe  = (__bf16*)d_ws;              // 1,048,576
    __bf16* wke  = wqe + 1048576;
    __bf16* wv16 = wke + 1048576;
    __bf16* wo16 = wv16 + 1048576;
    float*  bqe  = (float*)(wo16 + 1048576);   // 1024 f32
    float*  bke  = bqe + 1024;
    __bf16* q16  = (__bf16*)(bke + 1024);      // 4,194,304 each below
    __bf16* k16  = q16 + 4194304;
    __bf16* v16  = k16 + 4194304;
    __bf16* q2   = v16 + 4194304;
    __bf16* k2   = q2 + 4194304;
    __bf16* v2   = k2 + 4194304;
    __bf16* vt   = k16;   // alias: k16 dead after k2 GEMM
    __bf16* ctx  = q16;   // alias: q16 dead after q2 GEMM

    float* out   = (float*)d_out;
    float* probs = out + 4194304;

    cast3_kernel<<<dim3(2048, 3), 256, 0, stream>>>(query, key, value, q16, k16, v16);
    cast3_kernel<<<dim3(512, 2), 256, 0, stream>>>(Wv, Wo, nullptr, wv16, wo16, nullptr);

    eff_weight_kernel<<<4096, 256, 0, stream>>>(Wq, had, phase, wqe);
    eff_weight_kernel<<<4096, 256, 0, stream>>>(Wk, had, phase, wke);
    eff_bias_kernel<<<4, 256, 0, stream>>>(bq, had, phase, bqe);
    eff_bias_kernel<<<4, 256, 0, stream>>>(bk, had, phase, bke);

    dim3 gt(32, 8, 1);  // M=4096 / 128, N=1024 / 128
    gemm_bt_tiled<__bf16><<<gt, 256, 0, stream>>>(q16, wqe, q2, bqe, 1024, 1024);
    gemm_bt_tiled<__bf16><<<gt, 256, 0, stream>>>(k16, wke, k2, bke, 1024, 1024);
    gemm_bt_tiled<__bf16><<<gt, 256, 0, stream>>>(v16, wv16, v2, bv, 1024, 1024);

    transpose_v<<<1024, 256, 0, stream>>>(v2, vt);

    attn_kernel<<<dim3(64, 1, 64), 256, 0, stream>>>(q2, k2, probs);

    mix_kernel<<<4096, 256, 0, stream>>>(probs, mask);

    // ctx[b,q,h*64+d] = sum_k probs[b,h,q,k] * Vt[b,h,d,k]  (M=1024,N=64,K=1024 per z)
    gemm_bt<float, __bf16><<<dim3(16, 1, 64), 256, 0, stream>>>(
        probs, 1024, 16777216, 1048576,
        vt,    1024, 1048576,  65536,
        ctx,   1024, 1048576,  64,
        nullptr, 1024, 1.0f);

    // out = ctx @ Wo^T + bo
    gemm_bt_tiled<float><<<gt, 256, 0, stream>>>(ctx, wo16, out, bo, 1024, 1024);
}